// Round 1
// baseline (17059.808 us; speedup 1.0000x reference)
//
#include <hip/hip_runtime.h>
#include <math.h>

#define Bsz 256
#define Tn  512
#define En  512
#define Hn  1024
#define Cn  128
#define DECAY 0.9f

typedef unsigned short u16;
typedef unsigned int   u32;
typedef __attribute__((ext_vector_type(8))) short bf16x8;
typedef __attribute__((ext_vector_type(4))) float f32x4;

__device__ __forceinline__ u16 f2bf(float f) {
  union { float f; u32 u; } v; v.f = f;
  u32 x = v.u;
  return (u16)((x + 0x7fffu + ((x >> 16) & 1u)) >> 16);  // RNE
}

// ---------------- prep kernels ----------------

// Wc[4096][1536] = bf16([W_ih | W_hh]) row-major
__global__ void k_prep_wc(const float* __restrict__ Wih, const float* __restrict__ Whh,
                          u16* __restrict__ Wc) {
  int r = blockIdx.x;  // 0..4095
  const float* sih = Wih + (size_t)r * En;
  const float* shh = Whh + (size_t)r * Hn;
  u16* dst = Wc + (size_t)r * (En + Hn);
  for (int k = threadIdx.x; k < En + Hn; k += 256) {
    float v = (k < En) ? sih[k] : shh[k - En];
    dst[k] = f2bf(v);
  }
}

// Wl[512][1152] = bf16(W_lin)
__global__ void k_prep_wl(const float* __restrict__ Wlin, u16* __restrict__ Wl) {
  int e = blockIdx.x;  // 0..511
  for (int k = threadIdx.x; k < Hn + Cn; k += 256)
    Wl[(size_t)e * (Hn + Cn) + k] = f2bf(Wlin[(size_t)e * (Hn + Cn) + k]);
}

// biasg = b_ih+b_hh; nb[t] = #active rows; zero c state; zero both h buffers
__global__ void k_prep_misc(const float* __restrict__ bih, const float* __restrict__ bhh,
                            const int* __restrict__ seq,
                            float* __restrict__ biasg, int* __restrict__ nb,
                            float* __restrict__ cst, u16* __restrict__ hbuf) {
  const int total = 4096 + 512 + Bsz * Hn + 2 * Bsz * Hn;
  for (int i = blockIdx.x * 256 + threadIdx.x; i < total; i += gridDim.x * 256) {
    if (i < 4096) {
      biasg[i] = bih[i] + bhh[i];
    } else if (i < 4608) {
      int t = i - 4096, cnt = 0;
      for (int b = 0; b < Bsz; ++b) cnt += (seq[b] > t) ? 1 : 0;
      nb[t] = cnt;
    } else if (i < 4608 + Bsz * Hn) {
      cst[i - 4608] = 0.f;
    } else {
      hbuf[i - (4608 + Bsz * Hn)] = 0;
    }
  }
}

// cate EMA scan along t -> ce bf16 [B][T][C]
__global__ void k_ema(const float* __restrict__ cate, u16* __restrict__ ce) {
  int b = blockIdx.x;       // 0..255
  int ch = threadIdx.x;     // 0..127
  float prev = 0.f;
  for (int t = 0; t < Tn; ++t) {
    float v = cate[((size_t)b * Tn + t) * Cn + ch];
    float eff = (t == 0) ? v : (DECAY * prev + (1.f - DECAY) * v);
    prev = eff;
    ce[((size_t)b * Tn + t) * Cn + ch] = f2bf(eff);
  }
}

// out[b][t][e] = b_lin[e] everywhere (inactive rows keep this)
__global__ void k_prefill(float* __restrict__ out, const float* __restrict__ blin) {
  size_t i = (size_t)blockIdx.x * 256 + threadIdx.x;  // one float4 each
  int e = (int)((i * 4) & (En - 1));
  *(float4*)(out + i * 4) = *(const float4*)(blin + e);
}

// ---------------- per-timestep kernel ----------------
// blocks 0..255   : gate GEMM tile [32 batch x 32 hcol x 4 gates], K=1536, + state update, write h_t
// blocks 256..287 : output linear for step t-1: tile [32 batch x 128 e], K=1152
__global__ __launch_bounds__(256)
void k_step(int t,
            const float* __restrict__ x, const int* __restrict__ nb,
            const u16* __restrict__ Wc, const float* __restrict__ biasg,
            const u16* __restrict__ Wl, const float* __restrict__ blin,
            const u16* __restrict__ ce,
            float* __restrict__ cst, u16* __restrict__ hbuf,
            float* __restrict__ out) {
  __shared__ __align__(16) u16 As[32 * 40];       // A tile [32 rows][32 k], pad->40
  __shared__ __align__(16) u16 Bs[4 * 32 * 40];   // per-wave B tile [32 cols][32 k]
  __shared__ float gbuf[4 * 32 * 32];             // gate exchange i/f/g/o

  const int tid  = threadIdx.x;
  const int wave = tid >> 6, lane = tid & 63;
  const int nrow  = lane & 15;    // m/n within 16
  const int khalf = lane >> 4;    // 0..3
  const int kcol  = khalf * 8;

  // staging index helpers
  const int ar = tid >> 3;            // A: row 0..31
  const int ak = (tid & 7) * 4;       // A: 4 consecutive k
  const int bn = lane >> 1;           // B: col 0..31
  const int bh = (lane & 1) * 16;     // B: k half (16 elems)

  if (blockIdx.x < 256) {
    // ---------------- gate phase ----------------
    if (t >= Tn) return;
    const int nbt = nb[t];
    const int bm = blockIdx.x >> 5, hn = blockIdx.x & 31;
    const int b0 = bm * 32, j0 = hn * 32;
    if (b0 >= nbt) return;

    const u16* __restrict__ hprev = hbuf + (size_t)(t & 1) * (Bsz * Hn);
    u16* __restrict__ hnext = hbuf + (size_t)((t + 1) & 1) * (Bsz * Hn);

    f32x4 acc[2][2] = {};
    const u16* wrow = Wc + (size_t)(wave * Hn + j0 + bn) * 1536;

    for (int kc = 0; kc < 48; ++kc) {
      const int k0 = kc * 32;
      {  // A stage: [x_t | h_{t-1}] -> bf16 LDS
        const int k = k0 + ak;
        const int b = b0 + ar;
        if (k < En) {
          const float4 v = *(const float4*)(x + ((size_t)b * Tn + t) * En + k);
          ushort4 s;
          s.x = f2bf(v.x); s.y = f2bf(v.y); s.z = f2bf(v.z); s.w = f2bf(v.w);
          *(ushort4*)(As + ar * 40 + ak) = s;
        } else {
          *(ushort4*)(As + ar * 40 + ak) =
              *(const ushort4*)(hprev + (size_t)b * Hn + (k - En));
        }
      }
      {  // B stage: wave stages its own gate's 32 weight rows
        const u16* p = wrow + k0 + bh;
        uint4 v0 = *(const uint4*)p;
        uint4 v1 = *(const uint4*)(p + 8);
        u16* q = Bs + (wave * 32 + bn) * 40 + bh;
        *(uint4*)q = v0;
        *(uint4*)(q + 8) = v1;
      }
      __syncthreads();
      bf16x8 a0  = *(const bf16x8*)(As + nrow * 40 + kcol);
      bf16x8 a1  = *(const bf16x8*)(As + (16 + nrow) * 40 + kcol);
      bf16x8 bb0 = *(const bf16x8*)(Bs + (wave * 32 + nrow) * 40 + kcol);
      bf16x8 bb1 = *(const bf16x8*)(Bs + (wave * 32 + 16 + nrow) * 40 + kcol);
      acc[0][0] = __builtin_amdgcn_mfma_f32_16x16x32_bf16(a0, bb0, acc[0][0], 0, 0, 0);
      acc[0][1] = __builtin_amdgcn_mfma_f32_16x16x32_bf16(a0, bb1, acc[0][1], 0, 0, 0);
      acc[1][0] = __builtin_amdgcn_mfma_f32_16x16x32_bf16(a1, bb0, acc[1][0], 0, 0, 0);
      acc[1][1] = __builtin_amdgcn_mfma_f32_16x16x32_bf16(a1, bb1, acc[1][1], 0, 0, 0);
      __syncthreads();
    }

    // dump pre-activations (+bias) to LDS: gbuf[gate][m][n]
    for (int mi = 0; mi < 2; ++mi)
      for (int ni = 0; ni < 2; ++ni) {
        const int n = ni * 16 + nrow;
        const float bg = biasg[wave * Hn + j0 + n];
        for (int r = 0; r < 4; ++r) {
          const int m = mi * 16 + khalf * 4 + r;  // C/D layout: row=(lane>>4)*4+reg
          gbuf[wave * 1024 + m * 32 + n] = acc[mi][ni][r] + bg;
        }
      }
    __syncthreads();

    // pointwise LSTM cell update for the [32x32] (b,j) tile this block owns
    for (int p = tid; p < 1024; p += 256) {
      const int m = p >> 5, n = p & 31;
      const int b = b0 + m, j = j0 + n;
      const float gi = gbuf[0 * 1024 + p];
      const float gf = gbuf[1 * 1024 + p];
      const float gg = gbuf[2 * 1024 + p];
      const float go = gbuf[3 * 1024 + p];
      const float si = 1.f / (1.f + __expf(-gi));
      const float sf = 1.f / (1.f + __expf(-gf));
      const float tg = tanhf(gg);
      const float so = 1.f / (1.f + __expf(-go));
      const size_t idx = (size_t)b * Hn + j;
      const float cn = sf * cst[idx] + si * tg;
      cst[idx] = cn;
      hnext[idx] = f2bf(so * tanhf(cn));
    }
  } else {
    // ---------------- linear phase for step t-1 ----------------
    if (t == 0) return;
    const int tl = t - 1;
    const int nbl = nb[tl];
    const int lid = blockIdx.x - 256;  // 0..31
    const int bm = lid >> 2, en = lid & 3;
    const int b0 = bm * 32, e0 = en * 128;
    if (b0 >= nbl) return;

    const u16* __restrict__ hcur = hbuf + (size_t)(t & 1) * (Bsz * Hn);  // h_{t-1}

    f32x4 acc[2][2] = {};
    const u16* wrow = Wl + (size_t)(e0 + wave * 32 + bn) * 1152;

    for (int kc = 0; kc < 36; ++kc) {
      const int k0 = kc * 32;
      {  // A stage: [h_{t-1} | cate_eff_{t-1}]
        const int k = k0 + ak;
        const int b = b0 + ar;
        const u16* src = (k < Hn)
            ? (hcur + (size_t)b * Hn + k)
            : (ce + ((size_t)b * Tn + tl) * Cn + (k - Hn));
        *(ushort4*)(As + ar * 40 + ak) = *(const ushort4*)src;
      }
      {  // B stage
        const u16* p = wrow + k0 + bh;
        uint4 v0 = *(const uint4*)p;
        uint4 v1 = *(const uint4*)(p + 8);
        u16* q = Bs + (wave * 32 + bn) * 40 + bh;
        *(uint4*)q = v0;
        *(uint4*)(q + 8) = v1;
      }
      __syncthreads();
      bf16x8 a0  = *(const bf16x8*)(As + nrow * 40 + kcol);
      bf16x8 a1  = *(const bf16x8*)(As + (16 + nrow) * 40 + kcol);
      bf16x8 bb0 = *(const bf16x8*)(Bs + (wave * 32 + nrow) * 40 + kcol);
      bf16x8 bb1 = *(const bf16x8*)(Bs + (wave * 32 + 16 + nrow) * 40 + kcol);
      acc[0][0] = __builtin_amdgcn_mfma_f32_16x16x32_bf16(a0, bb0, acc[0][0], 0, 0, 0);
      acc[0][1] = __builtin_amdgcn_mfma_f32_16x16x32_bf16(a0, bb1, acc[0][1], 0, 0, 0);
      acc[1][0] = __builtin_amdgcn_mfma_f32_16x16x32_bf16(a1, bb0, acc[1][0], 0, 0, 0);
      acc[1][1] = __builtin_amdgcn_mfma_f32_16x16x32_bf16(a1, bb1, acc[1][1], 0, 0, 0);
      __syncthreads();
    }

    for (int mi = 0; mi < 2; ++mi)
      for (int ni = 0; ni < 2; ++ni) {
        const int e = e0 + wave * 32 + ni * 16 + nrow;
        const float bl = blin[e];
        for (int r = 0; r < 4; ++r) {
          const int b = b0 + mi * 16 + khalf * 4 + r;
          if (b < nbl)
            out[((size_t)b * Tn + tl) * En + e] = acc[mi][ni][r] + bl;
        }
      }
  }
}

// ---------------- launch ----------------
extern "C" void kernel_launch(void* const* d_in, const int* in_sizes, int n_in,
                              void* d_out, int out_size, void* d_ws, size_t ws_size,
                              hipStream_t stream) {
  const float* x    = (const float*)d_in[0];
  const float* cate = (const float*)d_in[1];
  const int*   seq  = (const int*)d_in[2];
  const float* Wih  = (const float*)d_in[3];
  const float* Whh  = (const float*)d_in[4];
  const float* bih  = (const float*)d_in[5];
  const float* bhh  = (const float*)d_in[6];
  const float* Wlin = (const float*)d_in[7];
  const float* blin = (const float*)d_in[8];
  float* out = (float*)d_out;

  char* w = (char*)d_ws;
  u16*   Wc    = (u16*)w;   w += (size_t)4096 * 1536 * 2;   // 12.58 MB
  u16*   Wl    = (u16*)w;   w += (size_t)512 * 1152 * 2;    //  1.18 MB
  float* biasg = (float*)w; w += (size_t)4096 * 4;
  int*   nb    = (int*)w;   w += (size_t)512 * 4;
  u16*   ce    = (u16*)w;   w += (size_t)Bsz * Tn * Cn * 2; // 33.55 MB
  float* cst   = (float*)w; w += (size_t)Bsz * Hn * 4;      //  1.05 MB
  u16*   hb    = (u16*)w;   w += (size_t)2 * Bsz * Hn * 2;  //  1.05 MB
  (void)ws_size; (void)in_sizes; (void)n_in; (void)out_size;

  k_prep_wc<<<4096, 256, 0, stream>>>(Wih, Whh, Wc);
  k_prep_wl<<<512, 256, 0, stream>>>(Wlin, Wl);
  k_prep_misc<<<3090, 256, 0, stream>>>(bih, bhh, seq, biasg, nb, cst, hb);
  k_ema<<<256, 128, 0, stream>>>(cate, ce);
  k_prefill<<<65536, 256, 0, stream>>>(out, blin);

  for (int t = 0; t <= Tn; ++t)
    k_step<<<288, 256, 0, stream>>>(t, x, nb, Wc, biasg, Wl, blin, ce, cst, hb, out);
}